// Round 8
// baseline (49.905 us; speedup 1.0000x reference)
//
#include <hip/hip_runtime.h>

namespace {

constexpr float kDT = 1e-3f;
constexpr int kB = 512;
constexpr int kT = 8192;
constexpr int kThr = 256;                 // 4 waves per block
constexpr int kSteps = 2;                 // steps per thread
constexpr int kChunk = kThr * kSteps;     // 512 steps per chunk
constexpr int kNC = kT / kChunk;          // 16 chunks per row
constexpr int kWaves = kThr / 64;         // 4
constexpr int kBlocks = kB * kNC;         // 8192

// Affine transform x' = M x + b packed {a,b,c,d,p,q}
struct Xf { float a, b, c, d, p, q; };

// Apply e (earlier) first, then l (later).
__device__ __forceinline__ Xf comp(const Xf& e, const Xf& l) {
  Xf o;
  o.a = l.a * e.a + l.b * e.c;
  o.b = l.a * e.b + l.b * e.d;
  o.c = l.c * e.a + l.d * e.c;
  o.d = l.c * e.b + l.d * e.d;
  o.p = l.a * e.p + l.b * e.q + l.p;
  o.q = l.c * e.p + l.d * e.q + l.q;
  return o;
}

__device__ __forceinline__ Xf shfl_up_xf(const Xf& v, int d) {
  Xf r;
  r.a = __shfl_up(v.a, d); r.b = __shfl_up(v.b, d);
  r.c = __shfl_up(v.c, d); r.d = __shfl_up(v.d, d);
  r.p = __shfl_up(v.p, d); r.q = __shfl_up(v.q, d);
  return r;
}

__device__ __forceinline__ Xf shfl_down_xf(const Xf& v, int d) {
  Xf r;
  r.a = __shfl_down(v.a, d); r.b = __shfl_down(v.b, d);
  r.c = __shfl_down(v.c, d); r.d = __shfl_down(v.d, d);
  r.p = __shfl_down(v.p, d); r.q = __shfl_down(v.q, d);
  return r;
}

__device__ __forceinline__ Xf make_xf(const float4 xv, float d0, float d1,
                                      float A00, float A01, float A10, float A11,
                                      float C00, float C01, float C10, float C11) {
  Xf m;
  m.a = 1.0f + kDT * (A00 - (xv.x * C00 + xv.y * C10));
  m.b =        kDT * (A01 - (xv.x * C01 + xv.y * C11));
  m.c =        kDT * (A10 - (xv.z * C00 + xv.w * C10));
  m.d = 1.0f + kDT * (A11 - (xv.z * C01 + xv.w * C11));
  m.p = xv.x * d0 + xv.y * d1;
  m.q = xv.z * d0 + xv.w * d1;
  return m;
}

// Kernel A: per-chunk composed transform -> tot[blk] (6 floats).
__global__ __launch_bounds__(kThr) void k_tot(
    const float* __restrict__ xic, const float* __restrict__ dy,
    const float* __restrict__ Ap, const float* __restrict__ Cp,
    float* __restrict__ tot) {
  __shared__ float sWT[kWaves][6];
  const int tid = threadIdx.x;
  const int lane = tid & 63;
  const int w = tid >> 6;
  const int blk = blockIdx.x;               // = r*kNC + c
  const size_t step0 = (size_t)blk * kChunk + 2 * tid;  // global step index

  const float4* X4 = reinterpret_cast<const float4*>(xic);
  const float4* D4 = reinterpret_cast<const float4*>(dy);

  const float A00 = Ap[0], A01 = Ap[1], A10 = Ap[2], A11 = Ap[3];
  const float C00 = Cp[0], C01 = Cp[1], C10 = Cp[2], C11 = Cp[3];

  const float4 xv0 = X4[step0];
  const float4 xv1 = X4[step0 + 1];
  const float4 dv = D4[step0 >> 1];

  const Xf s0 = make_xf(xv0, dv.x, dv.y, A00, A01, A10, A11, C00, C01, C10, C11);
  const Xf s1 = make_xf(xv1, dv.z, dv.w, A00, A01, A10, A11, C00, C01, C10, C11);
  Xf t = comp(s0, s1);

  // Lane-order tree reduce: lane 0 ends with the wave total.
#pragma unroll
  for (int d = 1; d < 64; d <<= 1) {
    const Xf r = shfl_down_xf(t, d);
    t = comp(t, r);
  }
  if (lane == 0) {
    sWT[w][0] = t.a; sWT[w][1] = t.b; sWT[w][2] = t.c;
    sWT[w][3] = t.d; sWT[w][4] = t.p; sWT[w][5] = t.q;
  }
  __syncthreads();

  if (tid == 0) {
    Xf pre{sWT[0][0], sWT[0][1], sWT[0][2], sWT[0][3], sWT[0][4], sWT[0][5]};
    for (int i = 1; i < kWaves; ++i) {
      const Xf wt{sWT[i][0], sWT[i][1], sWT[i][2],
                  sWT[i][3], sWT[i][4], sWT[i][5]};
      pre = comp(pre, wt);
    }
    float* o = tot + (size_t)blk * 6;
    o[0] = pre.a; o[1] = pre.b; o[2] = pre.c;
    o[3] = pre.d; o[4] = pre.p; o[5] = pre.q;
  }
}

// Kernel C: lookback over predecessor chunk totals + within-chunk scan + emit.
__global__ __launch_bounds__(kThr) void k_emit(
    const float* __restrict__ xic, const float* __restrict__ dy,
    const float* __restrict__ Ap, const float* __restrict__ Cp,
    const float* __restrict__ tot, float* __restrict__ out) {
  __shared__ float sWT[kWaves][6];
  const int tid = threadIdx.x;
  const int lane = tid & 63;
  const int w = tid >> 6;
  const int blk = blockIdx.x;
  const int r = blk / kNC;
  const int c = blk % kNC;
  const size_t step0 = (size_t)blk * kChunk + 2 * tid;

  const float4* X4 = reinterpret_cast<const float4*>(xic);
  const float4* D4 = reinterpret_cast<const float4*>(dy);
  float4* O4 = reinterpret_cast<float4*>(out);

  const float A00 = Ap[0], A01 = Ap[1], A10 = Ap[2], A11 = Ap[3];
  const float C00 = Cp[0], C01 = Cp[1], C10 = Cp[2], C11 = Cp[3];

  const float4 xv0 = X4[step0];
  const float4 xv1 = X4[step0 + 1];
  const float4 dv = D4[step0 >> 1];

  // Lookback: chunk entry state = (tot[r][c-1] ∘ ... ∘ tot[r][0]) (1,0).
  // Uniform addresses across the block -> broadcast loads, <=15 composes.
  float e0 = 1.0f, e1 = 0.0f;
  {
    Xf pre{1.f, 0.f, 0.f, 1.f, 0.f, 0.f};
    const float* tr = tot + (size_t)r * kNC * 6;
    for (int i = 0; i < c; ++i) {
      const Xf ti{tr[i * 6 + 0], tr[i * 6 + 1], tr[i * 6 + 2],
                  tr[i * 6 + 3], tr[i * 6 + 4], tr[i * 6 + 5]};
      pre = comp(pre, ti);
    }
    e0 = pre.a + pre.p;   // pre applied to (1,0)
    e1 = pre.c + pre.q;
  }

  const Xf s0 = make_xf(xv0, dv.x, dv.y, A00, A01, A10, A11, C00, C01, C10, C11);
  const Xf s1 = make_xf(xv1, dv.z, dv.w, A00, A01, A10, A11, C00, C01, C10, C11);
  const Xf tt = comp(s0, s1);

  // Wave inclusive shuffle scan over thread totals.
  Xf inc = tt;
#pragma unroll
  for (int d = 1; d < 64; d <<= 1) {
    const Xf rr = shfl_up_xf(inc, d);
    if (lane >= d) inc = comp(rr, inc);
  }
  if (lane == 63) {
    sWT[w][0] = inc.a; sWT[w][1] = inc.b; sWT[w][2] = inc.c;
    sWT[w][3] = inc.d; sWT[w][4] = inc.p; sWT[w][5] = inc.q;
  }
  __syncthreads();

  // Wave-exclusive prefix: compose wave totals 0..w-1 (redundant per thread,
  // <=3 composes, LDS broadcast reads, no second barrier).
  Xf Ew{1.f, 0.f, 0.f, 1.f, 0.f, 0.f};
  for (int i = 0; i < w; ++i) {
    const Xf wt{sWT[i][0], sWT[i][1], sWT[i][2],
                sWT[i][3], sWT[i][4], sWT[i][5]};
    Ew = comp(Ew, wt);
  }
  Xf le = shfl_up_xf(inc, 1);
  if (lane == 0) le = Xf{1.f, 0.f, 0.f, 1.f, 0.f, 0.f};
  const Xf ex = comp(Ew, le);   // block-exclusive prefix for this thread

  // State entering this thread's first step.
  const float x0 = ex.a * e0 + ex.b * e1 + ex.p;
  const float x1 = ex.c * e0 + ex.d * e1 + ex.q;

  float4 o;
  o.x = kDT * (C00 * x0 + C01 * x1);
  o.y = kDT * (C10 * x0 + C11 * x1);
  const float t0 = s0.a * x0 + s0.b * x1 + s0.p;
  const float t1 = s0.c * x0 + s0.d * x1 + s0.q;
  o.z = kDT * (C00 * t0 + C01 * t1);
  o.w = kDT * (C10 * t0 + C11 * t1);
  O4[step0 >> 1] = o;
}

}  // namespace

extern "C" void kernel_launch(void* const* d_in, const int* in_sizes, int n_in,
                              void* d_out, int out_size, void* d_ws,
                              size_t ws_size, hipStream_t stream) {
  const float* xic = (const float*)d_in[0];  // [B,T,2,2]
  const float* dy  = (const float*)d_in[1];  // [B,T,2]
  const float* Ap  = (const float*)d_in[2];  // [2,2] coeffs_A
  const float* Cp  = (const float*)d_in[3];  // [2,2] C
  float* out = (float*)d_out;                // [B,T,2]

  float* tot = (float*)d_ws;                 // kBlocks*6 floats = 192 KiB

  k_tot<<<kBlocks, kThr, 0, stream>>>(xic, dy, Ap, Cp, tot);
  k_emit<<<kBlocks, kThr, 0, stream>>>(xic, dy, Ap, Cp, tot, out);
}